// Round 13
// baseline (2428.083 us; speedup 1.0000x reference)
//
#include <hip/hip_runtime.h>

#define N_NODES 100000
#define R_REL   8
#define D_DIM   64
#define E_EDGES 3200000
#define NSEG    (N_NODES * R_REL)             // 800000
#define NB      391                            // dst buckets (dst>>8)
#define SEG_PER_BKT 2048                       // 256 nodes * 8 rel
#define BKT_CAP 9000                           // mean 8184 + ~9 sigma
#define P1_BLOCKS 512
#define P1_CHUNK  (E_EDGES / P1_BLOCKS)        // 6250
#define ESRC_CAP 1280                          // block run mean 1024, +8 sigma

typedef __attribute__((ext_vector_type(8))) short short8;   // 8 bf16 (4 VGPRs)
typedef __attribute__((ext_vector_type(4))) float f32x4;

__device__ __forceinline__ unsigned short f2bf(float f) {   // RNE float->bf16
    unsigned u = __float_as_uint(f);
    u += 0x7fffu + ((u >> 16) & 1u);
    return (unsigned short)(u >> 16);
}

__device__ __forceinline__ int epack(int s, int d, int r) {
    return (s << 11) | ((d & 255) << 3) | r;
}

// --- bucket cursor init ----------------------------------------------------
__global__ void init_cursor_kernel(int* __restrict__ bkt_cursor) {
    int t = blockIdx.x * 256 + threadIdx.x;
    if (t <= NB) bkt_cursor[t] = t * BKT_CAP;
}

// --- P1: partition edges into fixed-capacity dst-buckets (r2-proven) -------
__global__ void __launch_bounds__(256)
p1_scatter_kernel(const int* __restrict__ src, const int* __restrict__ dst,
                  const int* __restrict__ et, int* __restrict__ bkt_cursor,
                  int* __restrict__ packed) {
    __shared__ int hist[NB];
    __shared__ int cur[NB];
    int t = threadIdx.x;
    for (int i = t; i < NB; i += 256) hist[i] = 0;
    __syncthreads();
    int base = blockIdx.x * P1_CHUNK;
    for (int i = t; i < P1_CHUNK; i += 256)
        atomicAdd(&hist[dst[base + i] >> 8], 1);
    __syncthreads();
    for (int i = t; i < NB; i += 256) {
        int c = hist[i];
        cur[i] = c ? atomicAdd(&bkt_cursor[i], c) : 0;    // reserve block's run
    }
    __syncthreads();
    for (int i = t; i < P1_CHUNK; i += 256) {
        int e = base + i;
        int d = dst[e];
        int pos = atomicAdd(&cur[d >> 8], 1);
        packed[pos] = epack(src[e], d, et[e]);            // runs of ~16 -> line-merged
    }
}

// --- P2: quarter-bucket counting sort (r12) --------------------------------
// esrc entries now carry the relation: (sid<<3)|rel, consumed by v9 gather.
__global__ void __launch_bounds__(256)
p2_sort_kernel(const int* __restrict__ packed, const int* __restrict__ bkt_cursor,
               int* __restrict__ starts, int* __restrict__ ends, int* __restrict__ esrc) {
    __shared__ int scur[SEG_PER_BKT];                     // 8 KB
    __shared__ int wsum[4];
    int blk = blockIdx.x;
    int b  = blk >> 2, qq = blk & 3;
    int t  = threadIdx.x;
    int ebase = b * BKT_CAP;
    int eend  = bkt_cursor[b];                            // ebase + bucket count
    int segbase = b * SEG_PER_BKT;
#pragma unroll
    for (int i = 0; i < 8; ++i) scur[t + i * 256] = 0;
    __syncthreads();
    for (int e = ebase + t; e < eend; e += 256)           // pass 1: histogram
        atomicAdd(&scur[packed[e] & 2047], 1);
    __syncthreads();
    int loc[8], s = 0;
    int b8 = t * 8;
#pragma unroll
    for (int i = 0; i < 8; ++i) { loc[i] = scur[b8 + i]; s += loc[i]; }
    int lane = t & 63, wid = t >> 6;
    int x = s;                                             // wave inclusive scan
#pragma unroll
    for (int off = 1; off < 64; off <<= 1) {
        int y = __shfl_up(x, off, 64);
        if (lane >= off) x += y;
    }
    if (lane == 63) wsum[wid] = x;
    __syncthreads();                                       // also fences loc reads
    int woff = 0;
#pragma unroll
    for (int k = 0; k < 4; ++k) woff += (k < wid) ? wsum[k] : 0;
    int run = x + woff - s;                                // exclusive prefix
#pragma unroll
    for (int i = 0; i < 8; ++i) { scur[b8 + i] = run; run += loc[i]; }
    __syncthreads();
    // starts for own quarter's 512 segs (while scur = exclusive starts)
#pragma unroll
    for (int j = 0; j < 2; ++j) {
        int ls = qq * 512 + j * 256 + t;
        if (segbase + ls < NSEG) starts[segbase + ls] = ebase + scur[ls];
    }
    __syncthreads();
    for (int e = ebase + t; e < eend; e += 256) {          // pass 2: scatter own
        int p = packed[e];
        int ls = p & 2047;
        if ((ls >> 9) == qq) {
            int r = atomicAdd(&scur[ls], 1);
            esrc[ebase + r] = ((p >> 11) << 3) | (p & 7);  // (sid<<3)|rel
        }
    }
    __syncthreads();
#pragma unroll
    for (int j = 0; j < 2; ++j) {
        int ls = qq * 512 + j * 256 + t;
        if (segbase + ls < NSEG) ends[segbase + ls] = ebase + scur[ls];
    }
}

// --- merged prep: wprep W1 (b0-8), wprep W2 (b9-17), cvt emb (b18+) --------
__global__ void __launch_bounds__(256)
prep_kernel(const float* __restrict__ W1, const float* __restrict__ root1,
            const float* __restrict__ W2, const float* __restrict__ root2,
            const float* __restrict__ emb,
            unsigned short* __restrict__ wbuf1, unsigned short* __restrict__ wbuf2,
            unsigned short* __restrict__ embb) {
    int b = blockIdx.x;
    if (b < 18) {                                          // W transpose role
        int r = (b < 9) ? b : b - 9;
        const float* W    = (b < 9) ? W1 : W2;
        const float* root = (b < 9) ? root1 : root2;
        unsigned short* wbuf = (b < 9) ? wbuf1 : wbuf2;
        const float* src = (r < 8) ? (W + (size_t)r * 4096) : root;
        __shared__ float t[64][65];
        int a = threadIdx.x >> 2, c = threadIdx.x & 3;
#pragma unroll
        for (int i = 0; i < 4; ++i) {
            float4 v = *(const float4*)(src + a * 64 + c * 16 + i * 4);
            t[a][c * 16 + i * 4 + 0] = v.x;
            t[a][c * 16 + i * 4 + 1] = v.y;
            t[a][c * 16 + i * 4 + 2] = v.z;
            t[a][c * 16 + i * 4 + 3] = v.w;
        }
        __syncthreads();
        unsigned short* outrow = wbuf + (size_t)r * 4096 + a * 64;
#pragma unroll
        for (int i = 0; i < 4; ++i) {
            int k0 = c * 16 + i * 4;
            ushort4 o;
            o.x = f2bf(t[k0 + 0][a]); o.y = f2bf(t[k0 + 1][a]);
            o.z = f2bf(t[k0 + 2][a]); o.w = f2bf(t[k0 + 3][a]);
            *(ushort4*)(outrow + k0) = o;
        }
    } else {                                               // emb fp32 -> bf16
        size_t base = ((size_t)(b - 18) * 256 + threadIdx.x) * 8;
        float4 v0 = *(const float4*)(emb + base);
        float4 v1 = *(const float4*)(emb + base + 4);
        uint4 o;
        o.x = f2bf(v0.x) | ((unsigned)f2bf(v0.y) << 16);
        o.y = f2bf(v0.z) | ((unsigned)f2bf(v0.w) << 16);
        o.z = f2bf(v1.x) | ((unsigned)f2bf(v1.y) << 16);
        o.w = f2bf(v1.z) | ((unsigned)f2bf(v1.w) << 16);
        *(uint4*)(embb + base) = o;
    }
}

// --- fused layer v9: divergence-free gather via LDS f32 atomics ------------
// esrc carries (sid<<3)|rel. Gather is a FLAT loop: load row, 4x
// atomicAdd(&Asf[rel][g][dim]) -- no segment-boundary staircase, no
// divergent FLUSH serialization (the r4-r12 plateau's suspected binder).
// Mean+bf16-convert happens in a separate conflict-free pass, written
// in-place over Asf with v8's XOR swizzle; MFMA phase identical to v8.
// LDS: Asf 64KB + esrc 5KB -> 2 blocks/CU (16 waves): trades occupancy
// (24->16 waves) for a clean, deeply-pipelined inner loop.
__global__ void __launch_bounds__(512, 4)
fused_kernel(const unsigned short* __restrict__ hb, const int* __restrict__ esrc,
             const int* __restrict__ starts, const int* __restrict__ ends,
             const unsigned short* __restrict__ wbuf, const float* __restrict__ bias,
             void* __restrict__ out, int mode) {
    __shared__ float Asf[8 * 32 * 64];                     // 64 KB f32 accum
    __shared__ int esrc_lds[ESRC_CAP];                     // 5 KB
    int tid = threadIdx.x;
    int g   = tid >> 4;                                    // group 0..31 == local node
    int ml  = tid & 15;                                    // dim lane: dims 4ml..4ml+3
    int n0  = blockIdx.x * 32;
    int sblk = n0 * R_REL;

    // zero accumulators (strided: conflict-free) + stage esrc run
    {
        f32x4 z = {0.f, 0.f, 0.f, 0.f};
        f32x4* az = (f32x4*)Asf;
        for (int i = tid; i < 4096; i += 512) az[i] = z;
    }
    int E0 = starts[sblk];
    int L  = ends[sblk + 255] - E0;
    for (int i = tid; i < L; i += 512) esrc_lds[i] = esrc[E0 + i];
    __syncthreads();

    // ---- gather: flat accumulate over node (n0+g)'s edge run ----
    {
        int beg = starts[sblk + g * 8] - E0;
        int eN  = ends[sblk + g * 8 + 7] - E0;
        for (int e = beg; e < eN; e += 8) {
            int vs[8]; uint2 rows[8];
#pragma unroll
            for (int i = 0; i < 8; ++i) {
                int ee = e + i; ee = (ee < eN) ? ee : (eN - 1);
                vs[i] = esrc_lds[ee];
            }
#pragma unroll
            for (int i = 0; i < 8; ++i)
                rows[i] = *(const uint2*)(hb + (size_t)(vs[i] >> 3) * D_DIM + ml * 4);
#pragma unroll
            for (int i = 0; i < 8; ++i) {
                if (e + i < eN) {
                    float* ap = Asf + ((vs[i] & 7) * 2048 + g * 64 + ml * 4);
                    atomicAdd(ap + 0, __uint_as_float(rows[i].x << 16));
                    atomicAdd(ap + 1, __uint_as_float(rows[i].x & 0xffff0000u));
                    atomicAdd(ap + 2, __uint_as_float(rows[i].y << 16));
                    atomicAdd(ap + 3, __uint_as_float(rows[i].y & 0xffff0000u));
                }
            }
        }
    }

    // root A-fragments direct from global (latency hides under convert)
    int w  = tid >> 6;                                     // wave 0..7
    int kg = g & 3;
    int h  = w & 1;                                        // node-half
    int q  = w >> 1;                                       // dim-quarter
    const unsigned short* rp = hb + (size_t)(n0 + h * 16 + ml) * D_DIM + kg * 8;
    short8 RA0 = *(const short8*)(rp);
    short8 RA1 = *(const short8*)(rp + 32);

    __syncthreads();                                       // gather complete

    // ---- mean + bf16 convert, in-place (read all -> barrier -> write) ----
    // chunk i (f32x4): row pr=i>>4 (rel*32+node), ci=i&15. 8 chunks/thread.
    uint2 ob[8];
    unsigned waddr[8];
    {
        const f32x4* av = (const f32x4*)Asf;
#pragma unroll
        for (int k = 0; k < 8; ++k) {
            int i  = tid + k * 512;
            int pr = i >> 4, ci = i & 15;
            int node = pr & 31, rel = pr >> 5;
            int seg = sblk + node * 8 + rel;
            int cnt = ends[seg] - starts[seg];
            float inv = __builtin_amdgcn_rcpf(fmaxf((float)cnt, 1.0f));
            f32x4 v = av[i];
            ob[k].x = (unsigned)f2bf(v.x * inv) | ((unsigned)f2bf(v.y * inv) << 16);
            ob[k].y = (unsigned)f2bf(v.z * inv) | ((unsigned)f2bf(v.w * inv) << 16);
            waddr[k] = (unsigned)(pr * 128 + ci * 8) ^ (unsigned)((pr & 7) << 4);
        }
    }
    __syncthreads();                                       // all reads done
    {
        char* ab = (char*)Asf;
#pragma unroll
        for (int k = 0; k < 8; ++k)
            *(uint2*)(ab + waddr[k]) = ob[k];
    }
    __syncthreads();                                       // bf16 tile ready

    // ---- MFMA phases (identical to v8; A from swizzled bf16 tile) ----
    int arow = h * 16 + ml;
    unsigned asw = (unsigned)((arow & 7) << 4);
    const char* asb = (const char*)Asf;

    f32x4 acc = {0, 0, 0, 0};
#pragma unroll 1
    for (int p = 0; p < 8; ++p) {
        unsigned base = (unsigned)((p * 32 + arow) * 128);
        short8 A0 = *(const short8*)(asb + ((base + kg * 16) ^ asw));
        short8 A1 = *(const short8*)(asb + ((base + 64 + kg * 16) ^ asw));
        const unsigned short* bp = wbuf + (size_t)p * 4096 + (q * 16 + ml) * 64 + kg * 8;
        short8 B0 = *(const short8*)(bp);                  // L1/L2-hot
        short8 B1 = *(const short8*)(bp + 32);
        acc = __builtin_amdgcn_mfma_f32_16x16x32_bf16(A0, B0, acc, 0, 0, 0);
        acc = __builtin_amdgcn_mfma_f32_16x16x32_bf16(A1, B1, acc, 0, 0, 0);
    }
    {   // root phase
        const unsigned short* bp = wbuf + (size_t)8 * 4096 + (q * 16 + ml) * 64 + kg * 8;
        short8 B0 = *(const short8*)(bp);
        short8 B1 = *(const short8*)(bp + 32);
        acc = __builtin_amdgcn_mfma_f32_16x16x32_bf16(RA0, B0, acc, 0, 0, 0);
        acc = __builtin_amdgcn_mfma_f32_16x16x32_bf16(RA1, B1, acc, 0, 0, 0);
    }

    // epilogue: C layout col=ml (dim), row=kg*4+reg (node) [verified]
    float bv = bias[q * 16 + ml];
#pragma unroll
    for (int rg = 0; rg < 4; ++rg) {
        int node = n0 + h * 16 + kg * 4 + rg;
        float v = acc[rg] + bv;
        if (mode) {
            v = fmaxf(v, 0.f);
            ((unsigned short*)out)[(size_t)node * D_DIM + q * 16 + ml] = f2bf(v);
        } else {
            ((float*)out)[(size_t)node * D_DIM + q * 16 + ml] = v;
        }
    }
}

// --- launch ---------------------------------------------------------------

extern "C" void kernel_launch(void* const* d_in, const int* in_sizes, int n_in,
                              void* d_out, int out_size, void* d_ws, size_t ws_size,
                              hipStream_t stream) {
    const int*   ei    = (const int*)d_in[1];
    const int*   src   = ei;
    const int*   dst   = ei + E_EDGES;
    const int*   et    = (const int*)d_in[2];
    const float* emb   = (const float*)d_in[3];   // x = arange(N): identity remap
    const float* W1    = (const float*)d_in[4];
    const float* root1 = (const float*)d_in[5];
    const float* b1    = (const float*)d_in[6];
    const float* W2    = (const float*)d_in[7];
    const float* root2 = (const float*)d_in[8];
    const float* b2    = (const float*)d_in[9];
    float*       out   = (float*)d_out;

    // workspace layout (bf16 blocks first: all 16B-aligned)
    unsigned short* embb   = (unsigned short*)d_ws;                      // [N*64] bf16
    unsigned short* h1b    = embb + (size_t)N_NODES * D_DIM;             // [N*64] bf16
    unsigned short* wbuf1  = h1b + (size_t)N_NODES * D_DIM;              // [9*4096] bf16
    unsigned short* wbuf2  = wbuf1 + 9 * 4096;
    int*            starts = (int*)(wbuf2 + 9 * 4096);                   // [NSEG]
    int*            ends   = starts + NSEG;                              // [NSEG]
    int*            packed = ends + NSEG;                                // [NB*CAP]
    int*            esrc   = packed + (size_t)NB * BKT_CAP;              // [NB*CAP]
    int*            bkt_cursor = esrc + (size_t)NB * BKT_CAP;            // [NB+1]

    // ---- CSR build: fixed-capacity buckets ----
    init_cursor_kernel<<<2, 256, 0, stream>>>(bkt_cursor);
    p1_scatter_kernel <<<P1_BLOCKS, 256, 0, stream>>>(src, dst, et, bkt_cursor, packed);
    p2_sort_kernel    <<<NB * 4, 256, 0, stream>>>(packed, bkt_cursor, starts, ends, esrc);

    // ---- merged prep: W transpose x2 + emb bf16 cvt ----
    prep_kernel<<<18 + (N_NODES * D_DIM) / 2048, 256, 0, stream>>>(
        W1, root1, W2, root2, emb, wbuf1, wbuf2, embb);

    const int blocks = N_NODES / 32;             // 3125 exact

    // ---- layer 1: emb -> h1b (ReLU, bf16) ----
    fused_kernel<<<blocks, 512, 0, stream>>>(embb, esrc, starts, ends, wbuf1, b1, h1b, 1);
    // ---- layer 2: h1b -> out (fp32) ----
    fused_kernel<<<blocks, 512, 0, stream>>>(h1b, esrc, starts, ends, wbuf2, b2, out, 0);
}

// Round 14
// 400.941 us; speedup vs baseline: 6.0560x; 6.0560x over previous
//
#include <hip/hip_runtime.h>

#define N_NODES 100000
#define R_REL   8
#define D_DIM   64
#define E_EDGES 3200000
#define NSEG    (N_NODES * R_REL)             // 800000
#define NB      782                            // dst buckets (dst>>7)
#define SEG_PER_BKT 1024                       // 128 nodes * 8 rel
#define BKT_CAP 4800                           // mean 4092 + ~11 sigma
#define P1_BLOCKS 625
#define P1_CHUNK  5120                         // 625 * 5120 = 3.2M
#define ESRC_CAP 1280                          // block run mean 1024, +8 sigma

typedef __attribute__((ext_vector_type(8))) short short8;   // 8 bf16 (4 VGPRs)
typedef __attribute__((ext_vector_type(4))) float f32x4;
typedef __attribute__((ext_vector_type(2))) float f32x2;

__device__ __forceinline__ unsigned short f2bf(float f) {   // RNE float->bf16
    unsigned u = __float_as_uint(f);
    u += 0x7fffu + ((u >> 16) & 1u);
    return (unsigned short)(u >> 16);
}

__device__ __forceinline__ int epack(int s, int d, int r) {
    return (s << 10) | ((d & 127) << 3) | r;
}

// --- bucket cursor init ----------------------------------------------------
__global__ void init_cursor_kernel(int* __restrict__ bkt_cursor) {
    int t = blockIdx.x * 256 + threadIdx.x;
    if (t <= NB) bkt_cursor[t] = t * BKT_CAP;
}

// --- P1: partition edges into fixed-capacity dst-buckets (int4 loads) ------
__global__ void __launch_bounds__(256)
p1_scatter_kernel(const int* __restrict__ src, const int* __restrict__ dst,
                  const int* __restrict__ et, int* __restrict__ bkt_cursor,
                  int* __restrict__ packed) {
    __shared__ int hist[NB];
    __shared__ int cur[NB];
    int t = threadIdx.x;
    for (int i = t; i < NB; i += 256) hist[i] = 0;
    __syncthreads();
    int base = blockIdx.x * P1_CHUNK;
    for (int i = t * 4; i < P1_CHUNK; i += 1024) {         // 5 exact iters
        int4 d4 = *(const int4*)(dst + base + i);
        atomicAdd(&hist[d4.x >> 7], 1);
        atomicAdd(&hist[d4.y >> 7], 1);
        atomicAdd(&hist[d4.z >> 7], 1);
        atomicAdd(&hist[d4.w >> 7], 1);
    }
    __syncthreads();
    for (int i = t; i < NB; i += 256) {
        int c = hist[i];
        cur[i] = c ? atomicAdd(&bkt_cursor[i], c) : 0;    // reserve block's run
    }
    __syncthreads();
    for (int i = t * 4; i < P1_CHUNK; i += 1024) {
        int4 s4 = *(const int4*)(src + base + i);
        int4 d4 = *(const int4*)(dst + base + i);
        int4 t4 = *(const int4*)(et  + base + i);
        int p0 = atomicAdd(&cur[d4.x >> 7], 1); packed[p0] = epack(s4.x, d4.x, t4.x);
        int p1 = atomicAdd(&cur[d4.y >> 7], 1); packed[p1] = epack(s4.y, d4.y, t4.y);
        int p2 = atomicAdd(&cur[d4.z >> 7], 1); packed[p2] = epack(s4.z, d4.z, t4.z);
        int p3 = atomicAdd(&cur[d4.w >> 7], 1); packed[p3] = epack(s4.w, d4.w, t4.w);
    }
}

// --- P2: per-bucket counting sort, packed staged in LDS --------------------
__global__ void __launch_bounds__(256)
p2_sort_kernel(const int* __restrict__ packed, const int* __restrict__ bkt_cursor,
               int* __restrict__ starts, int* __restrict__ ends, int* __restrict__ esrc) {
    __shared__ int spk[BKT_CAP];                          // 19.2 KB
    __shared__ int shist[SEG_PER_BKT];
    __shared__ int scur[SEG_PER_BKT];
    __shared__ int stmp[256];
    int b = blockIdx.x;
    int t = threadIdx.x;
    int ebase = b * BKT_CAP;
    int ecnt  = bkt_cursor[b] - ebase;                    // bucket edge count
    int segbase = b * SEG_PER_BKT;
    int nseg = NSEG - segbase; if (nseg > SEG_PER_BKT) nseg = SEG_PER_BKT;
#pragma unroll
    for (int i = 0; i < 4; ++i) shist[t + i * 256] = 0;
    __syncthreads();
    for (int i = t; i < ecnt; i += 256) {                 // single global read
        int p = packed[ebase + i];
        spk[i] = p;
        atomicAdd(&shist[p & 1023], 1);
    }
    __syncthreads();
    int loc[4], s = 0;
    int b4 = t * 4;
#pragma unroll
    for (int i = 0; i < 4; ++i) { loc[i] = shist[b4 + i]; s += loc[i]; }
    stmp[t] = s;
    __syncthreads();
    for (int off = 1; off < 256; off <<= 1) {
        int x = (t >= off) ? stmp[t - off] : 0;
        __syncthreads();
        stmp[t] += x;
        __syncthreads();
    }
    int run = (t == 0) ? 0 : stmp[t - 1];
#pragma unroll
    for (int i = 0; i < 4; ++i) {
        shist[b4 + i] = run; scur[b4 + i] = run;
        run += loc[i];
    }
    __syncthreads();
    for (int i = t; i < nseg; i += 256)
        starts[segbase + i] = ebase + shist[i];
    for (int i = t; i < ecnt; i += 256) {
        int p = spk[i];
        int r = atomicAdd(&scur[p & 1023], 1);
        esrc[ebase + r] = p >> 10;                        // 19KB window, L2-merged
    }
    __syncthreads();
    for (int i = t; i < nseg; i += 256)
        ends[segbase + i] = ebase + scur[i];              // scur = start + count now
}

// --- merged prep: wprep W1 (b0-8), wprep W2 (b9-17), cvt emb (b18+) --------
__global__ void __launch_bounds__(256)
prep_kernel(const float* __restrict__ W1, const float* __restrict__ root1,
            const float* __restrict__ W2, const float* __restrict__ root2,
            const float* __restrict__ emb,
            unsigned short* __restrict__ wbuf1, unsigned short* __restrict__ wbuf2,
            unsigned short* __restrict__ embb) {
    int b = blockIdx.x;
    if (b < 18) {                                          // W transpose role
        int r = (b < 9) ? b : b - 9;
        const float* W    = (b < 9) ? W1 : W2;
        const float* root = (b < 9) ? root1 : root2;
        unsigned short* wbuf = (b < 9) ? wbuf1 : wbuf2;
        const float* src = (r < 8) ? (W + (size_t)r * 4096) : root;
        __shared__ float t[64][65];
        int a = threadIdx.x >> 2, c = threadIdx.x & 3;
#pragma unroll
        for (int i = 0; i < 4; ++i) {
            float4 v = *(const float4*)(src + a * 64 + c * 16 + i * 4);
            t[a][c * 16 + i * 4 + 0] = v.x;
            t[a][c * 16 + i * 4 + 1] = v.y;
            t[a][c * 16 + i * 4 + 2] = v.z;
            t[a][c * 16 + i * 4 + 3] = v.w;
        }
        __syncthreads();
        unsigned short* outrow = wbuf + (size_t)r * 4096 + a * 64;
#pragma unroll
        for (int i = 0; i < 4; ++i) {
            int k0 = c * 16 + i * 4;
            ushort4 o;
            o.x = f2bf(t[k0 + 0][a]); o.y = f2bf(t[k0 + 1][a]);
            o.z = f2bf(t[k0 + 2][a]); o.w = f2bf(t[k0 + 3][a]);
            *(ushort4*)(outrow + k0) = o;
        }
    } else {                                               // emb fp32 -> bf16
        size_t base = ((size_t)(b - 18) * 256 + threadIdx.x) * 8;
        float4 v0 = *(const float4*)(emb + base);
        float4 v1 = *(const float4*)(emb + base + 4);
        uint4 o;
        o.x = f2bf(v0.x) | ((unsigned)f2bf(v0.y) << 16);
        o.y = f2bf(v0.z) | ((unsigned)f2bf(v0.w) << 16);
        o.z = f2bf(v1.x) | ((unsigned)f2bf(v1.y) << 16);
        o.w = f2bf(v1.z) | ((unsigned)f2bf(v1.w) << 16);
        *(uint4*)(embb + base) = o;
    }
}

// --- fused layer v8 (proven best: r9, 111.5us): swizzled As, 37KB LDS ------
__global__ void __launch_bounds__(512, 8)
fused_kernel(const unsigned short* __restrict__ hb, const int* __restrict__ esrc,
             const int* __restrict__ starts, const int* __restrict__ ends,
             const unsigned short* __restrict__ wbuf, const float* __restrict__ bias,
             void* __restrict__ out, int mode) {
    __shared__ unsigned short As[8][32][64];               // 32 KB, swizzled
    __shared__ int esrc_lds[ESRC_CAP];                     // 5 KB
    int tid = threadIdx.x;
    int g   = tid >> 4;                                    // group 0..31 == local node
    int ml  = tid & 15;                                    // dim lane: dims 4ml..4ml+3
    int n0  = blockIdx.x * 32;
    int sblk = n0 * R_REL;

    // stage block's edge-id run (contiguous within its dst-bucket)
    int E0 = starts[sblk];
    int L  = ends[sblk + 255] - E0;
    for (int i = tid; i < L; i += 512) esrc_lds[i] = esrc[E0 + i];
    __syncthreads();

    // ---- gather: stream node (n0+g)'s full edge run ----
    {
        int segb = sblk + g * R_REL;
        int4 eA = *(const int4*)(ends + segb);             // ends[segb+0..3]
        int4 eB = *(const int4*)(ends + segb + 4);         // ends[segb+4..7]
        int beg_cur = starts[segb] - E0;                   // local coords
        eA.x -= E0; eA.y -= E0; eA.z -= E0; eA.w -= E0;
        eB.x -= E0; eB.y -= E0; eB.z -= E0; eB.w -= E0;
        int end_cur = eA.x;
        int eN = eB.w;
        int r = 0;
        f32x2 a01 = {0.f, 0.f}, a23 = {0.f, 0.f};
        unsigned swz = (unsigned)((g & 7) << 4);           // row-XOR swizzle

#define FLUSH()                                                          \
    do {                                                                 \
        float inv = __builtin_amdgcn_rcpf(                               \
            fmaxf((float)(end_cur - beg_cur), 1.0f));                    \
        ushort4 o;                                                       \
        o.x = f2bf(a01.x * inv); o.y = f2bf(a01.y * inv);                \
        o.z = f2bf(a23.x * inv); o.w = f2bf(a23.y * inv);                \
        *(ushort4*)((char*)As +                                          \
            ((unsigned)((r * 32 + g) * 128 + ml * 8) ^ swz)) = o;        \
        a01 = (f32x2){0.f, 0.f}; a23 = (f32x2){0.f, 0.f};                \
        ++r;                                                             \
        beg_cur = end_cur;                                               \
        end_cur = (r == 1) ? eA.y : (r == 2) ? eA.z : (r == 3) ? eA.w :  \
                  (r == 4) ? eB.x : (r == 5) ? eB.y : (r == 6) ? eB.z :  \
                  (r == 7) ? eB.w : 0x7fffffff;                          \
    } while (0)

        int e = beg_cur;
        while (e < eN) {
            int m = eN - e; if (m > 8) m = 8;
            uint2 rows[8];
#pragma unroll
            for (int i = 0; i < 8; ++i) {
                int ee = e + i; ee = (ee < eN) ? ee : (eN - 1);
                int sid = esrc_lds[ee];                    // LDS: short dep chain
                rows[i] = *(const uint2*)(hb + (size_t)sid * D_DIM + ml * 4);
            }
#pragma unroll
            for (int i = 0; i < 8; ++i) {
                if (i < m) {
                    while (e + i >= end_cur) FLUSH();
                    f32x2 u, v;
                    u.x = __uint_as_float(rows[i].x << 16);
                    u.y = __uint_as_float(rows[i].x & 0xffff0000u);
                    v.x = __uint_as_float(rows[i].y << 16);
                    v.y = __uint_as_float(rows[i].y & 0xffff0000u);
                    a01 += u;
                    a23 += v;
                }
            }
            e += m;
        }
        while (r < 8) FLUSH();
#undef FLUSH
    }

    // ---- wave/fragment ids for MFMA ----
    int w  = tid >> 6;                                     // wave 0..7
    int kg = g & 3;                                        // k-group within wave
    int h  = w & 1;                                        // node-half (16 nodes)
    int q  = w >> 1;                                       // dim-quarter (16 dims)

    // root A-fragments direct from global (latency hides under MFMA phases)
    const unsigned short* rp = hb + (size_t)(n0 + h * 16 + ml) * D_DIM + kg * 8;
    short8 RA0 = *(const short8*)(rp);
    short8 RA1 = *(const short8*)(rp + 32);

    __syncthreads();

    int arow = h * 16 + ml;
    unsigned asw = (unsigned)((arow & 7) << 4);            // read-side swizzle
    const char* asb = (const char*)As;

    f32x4 acc = {0, 0, 0, 0};
#pragma unroll 1
    for (int p = 0; p < 8; ++p) {
        unsigned base = (unsigned)((p * 32 + arow) * 128);
        short8 A0 = *(const short8*)(asb + ((base + kg * 16) ^ asw));
        short8 A1 = *(const short8*)(asb + ((base + 64 + kg * 16) ^ asw));
        const unsigned short* bp = wbuf + (size_t)p * 4096 + (q * 16 + ml) * 64 + kg * 8;
        short8 B0 = *(const short8*)(bp);                  // L1/L2-hot
        short8 B1 = *(const short8*)(bp + 32);
        acc = __builtin_amdgcn_mfma_f32_16x16x32_bf16(A0, B0, acc, 0, 0, 0);
        acc = __builtin_amdgcn_mfma_f32_16x16x32_bf16(A1, B1, acc, 0, 0, 0);
    }
    {   // root phase
        const unsigned short* bp = wbuf + (size_t)8 * 4096 + (q * 16 + ml) * 64 + kg * 8;
        short8 B0 = *(const short8*)(bp);
        short8 B1 = *(const short8*)(bp + 32);
        acc = __builtin_amdgcn_mfma_f32_16x16x32_bf16(RA0, B0, acc, 0, 0, 0);
        acc = __builtin_amdgcn_mfma_f32_16x16x32_bf16(RA1, B1, acc, 0, 0, 0);
    }

    // epilogue: C layout col=ml (dim), row=kg*4+reg (node) [verified]
    float bv = bias[q * 16 + ml];
#pragma unroll
    for (int rg = 0; rg < 4; ++rg) {
        int node = n0 + h * 16 + kg * 4 + rg;
        float v = acc[rg] + bv;
        if (mode) {
            v = fmaxf(v, 0.f);
            ((unsigned short*)out)[(size_t)node * D_DIM + q * 16 + ml] = f2bf(v);
        } else {
            ((float*)out)[(size_t)node * D_DIM + q * 16 + ml] = v;
        }
    }
}

// --- launch ---------------------------------------------------------------

extern "C" void kernel_launch(void* const* d_in, const int* in_sizes, int n_in,
                              void* d_out, int out_size, void* d_ws, size_t ws_size,
                              hipStream_t stream) {
    const int*   ei    = (const int*)d_in[1];
    const int*   src   = ei;
    const int*   dst   = ei + E_EDGES;
    const int*   et    = (const int*)d_in[2];
    const float* emb   = (const float*)d_in[3];   // x = arange(N): identity remap
    const float* W1    = (const float*)d_in[4];
    const float* root1 = (const float*)d_in[5];
    const float* b1    = (const float*)d_in[6];
    const float* W2    = (const float*)d_in[7];
    const float* root2 = (const float*)d_in[8];
    const float* b2    = (const float*)d_in[9];
    float*       out   = (float*)d_out;

    // workspace layout (bf16 blocks first: all 16B-aligned)
    unsigned short* embb   = (unsigned short*)d_ws;                      // [N*64] bf16
    unsigned short* h1b    = embb + (size_t)N_NODES * D_DIM;             // [N*64] bf16
    unsigned short* wbuf1  = h1b + (size_t)N_NODES * D_DIM;              // [9*4096] bf16
    unsigned short* wbuf2  = wbuf1 + 9 * 4096;
    int*            starts = (int*)(wbuf2 + 9 * 4096);                   // [NSEG]
    int*            ends   = starts + NSEG;                              // [NSEG]
    int*            packed = ends + NSEG;                                // [NB*CAP]
    int*            esrc   = packed + (size_t)NB * BKT_CAP;              // [NB*CAP]
    int*            bkt_cursor = esrc + (size_t)NB * BKT_CAP;            // [NB+1]

    // ---- CSR build: fixed-capacity buckets ----
    init_cursor_kernel<<<4, 256, 0, stream>>>(bkt_cursor);
    p1_scatter_kernel <<<P1_BLOCKS, 256, 0, stream>>>(src, dst, et, bkt_cursor, packed);
    p2_sort_kernel    <<<NB, 256, 0, stream>>>(packed, bkt_cursor, starts, ends, esrc);

    // ---- merged prep: W transpose x2 + emb bf16 cvt ----
    prep_kernel<<<18 + (N_NODES * D_DIM) / 2048, 256, 0, stream>>>(
        W1, root1, W2, root2, emb, wbuf1, wbuf2, embb);

    const int blocks = N_NODES / 32;             // 3125 exact

    // ---- layer 1: emb -> h1b (ReLU, bf16) ----
    fused_kernel<<<blocks, 512, 0, stream>>>(embb, esrc, starts, ends, wbuf1, b1, h1b, 1);
    // ---- layer 2: h1b -> out (fp32) ----
    fused_kernel<<<blocks, 512, 0, stream>>>(h1b, esrc, starts, ends, wbuf2, b2, out, 0);
}